// Round 1
// baseline (62.868 us; speedup 1.0000x reference)
//
#include <hip/hip_runtime.h>
#include <math.h>

#define NUM_DIRS 720
#define CF 512            // faces per chunk in scan kernel
#define NPAIRS 12         // 3 measurements x 4 batches

// ---------------------------------------------------------------------------
// Kernel A: mass partial sums.  vol per face, summed per batch via atomics.
// ---------------------------------------------------------------------------
__global__ __launch_bounds__(256) void mass_kernel(const float* __restrict__ tris,
                                                   int F,
                                                   float* __restrict__ mass_acc) {
    int b = blockIdx.y;
    float local = 0.f;
    for (int f = blockIdx.x * blockDim.x + threadIdx.x; f < F;
         f += gridDim.x * blockDim.x) {
        const float* t = tris + ((size_t)(b * F + f)) * 9;
        float x0 = t[0], y0 = t[1], z0 = t[2];
        float x1 = t[3], y1 = t[4], z1 = t[5];
        float x2 = t[6], y2 = t[7], z2 = t[8];
        float vol = -x2 * y1 * z0 + x1 * y2 * z0 + x2 * y0 * z1
                    - x0 * y2 * z1 - x1 * y0 * z2 + x0 * y1 * z2;
        local += vol;
    }
    // wave reduce (64) then cross-wave
    for (int off = 32; off; off >>= 1) local += __shfl_down(local, off, 64);
    __shared__ float wsum[4];
    int lane = threadIdx.x & 63, w = threadIdx.x >> 6;
    if (lane == 0) wsum[w] = local;
    __syncthreads();
    if (threadIdx.x == 0) {
        float s = wsum[0] + wsum[1] + wsum[2] + wsum[3];
        atomicAdd(&mass_acc[b], s);
    }
}

// ---------------------------------------------------------------------------
// Kernel B: cross-section + per-direction argmax scan.
// grid = (nChunks, 12).  pair = m*4+b.  Compacts valid edge-plane crossings
// into LDS, then each thread owns up to 3 directions and scans the compact
// list (broadcast LDS reads).  Global merge via packed u64 atomicMax:
//   [ orderable(proj) : 32 | (0xFFFFFFFF - point_idx) : 32 ]
// so larger proj wins, ties -> smaller point index (matches jnp.argmax).
// ---------------------------------------------------------------------------
__global__ __launch_bounds__(256) void scan_kernel(
    const float* __restrict__ tris, int F,
    const float* __restrict__ bc0, const float* __restrict__ bc1,
    const float* __restrict__ bc2,
    const int* __restrict__ fi0, const int* __restrict__ fi1,
    const int* __restrict__ fi2,
    unsigned long long* __restrict__ best) {
    int pair = blockIdx.y;
    int m = pair >> 2, b = pair & 3;
    const float* bc = (m == 0) ? bc0 : ((m == 1) ? bc1 : bc2);
    int fidx = (m == 0) ? fi0[0] : ((m == 1) ? fi1[0] : fi2[0]);
    const float* vt = tris + ((size_t)(b * F + fidx)) * 9;
    float h = bc[0] * vt[1] + bc[1] * vt[4] + bc[2] * vt[7];

    __shared__ float sx[3 * CF], sz[3 * CF];
    __shared__ int sidx[3 * CF];
    __shared__ int cnt;
    if (threadIdx.x == 0) cnt = 0;
    __syncthreads();

    int f0 = blockIdx.x * CF;
    int fend = min(f0 + CF, F);
    for (int f = f0 + threadIdx.x; f < fend; f += blockDim.x) {
        const float* t = tris + ((size_t)(b * F + f)) * 9;
        float v[9];
#pragma unroll
        for (int i = 0; i < 9; i++) v[i] = t[i];
#pragma unroll
        for (int k = 0; k < 3; k++) {
            int j = (k == 2) ? 0 : (k + 1);
            float yi = v[k * 3 + 1], yj = v[j * 3 + 1];
            if ((yi - h) * (yj - h) < 0.f) {
                float denom = yj - yi;
                float safe = (fabsf(denom) > 1e-12f) ? denom : 1e-12f;
                float tt = (h - yi) / safe;
                tt = fminf(fmaxf(tt, 0.f), 1.f);
                float px = v[k * 3 + 0] + tt * (v[j * 3 + 0] - v[k * 3 + 0]);
                float pz = v[k * 3 + 2] + tt * (v[j * 3 + 2] - v[k * 3 + 2]);
                int n = atomicAdd(&cnt, 1);
                sx[n] = px;
                sz[n] = pz;
                sidx[n] = f * 3 + k;
            }
        }
    }
    __syncthreads();
    int n = cnt;
    if (n == 0) return;

    const float dth = (float)(6.283185307179586476925287 / 720.0);
    int d0 = threadIdx.x, d1 = threadIdx.x + 256, d2 = threadIdx.x + 512;
    float c0 = 0.f, s0 = 0.f, c1 = 0.f, s1 = 0.f, c2 = 0.f, s2 = 0.f;
    {
        float th;
        th = (float)d0 * dth; sincosf(th, &s0, &c0);
        if (d1 < NUM_DIRS) { th = (float)d1 * dth; sincosf(th, &s1, &c1); }
        if (d2 < NUM_DIRS) { th = (float)d2 * dth; sincosf(th, &s2, &c2); }
    }
    float bp0 = -INFINITY, bp1 = -INFINITY, bp2 = -INFINITY;
    int bs0 = 0, bs1 = 0, bs2 = 0;
#pragma unroll 4
    for (int i = 0; i < n; i++) {
        float x = sx[i], z = sz[i];
        float p0 = x * c0 + z * s0;
        float p1 = x * c1 + z * s1;
        float p2 = x * c2 + z * s2;
        if (p0 > bp0) { bp0 = p0; bs0 = i; }
        if (p1 > bp1) { bp1 = p1; bs1 = i; }
        if (p2 > bp2) { bp2 = p2; bs2 = i; }
    }
#pragma unroll
    for (int q = 0; q < 3; q++) {
        int d = (q == 0) ? d0 : ((q == 1) ? d1 : d2);
        if (d >= NUM_DIRS) continue;
        float bp = (q == 0) ? bp0 : ((q == 1) ? bp1 : bp2);
        int bs = (q == 0) ? bs0 : ((q == 1) ? bs1 : bs2);
        unsigned int idx = (unsigned int)sidx[bs];
        unsigned int pb = __float_as_uint(bp);
        pb = (pb & 0x80000000u) ? ~pb : (pb | 0x80000000u);
        unsigned long long e =
            ((unsigned long long)pb << 32) |
            (unsigned long long)(0xFFFFFFFFu - idx);
        atomicMax(&best[pair * NUM_DIRS + d], e);
    }
}

// ---------------------------------------------------------------------------
// Kernel C: finalize.  Decode per-dir winners, recompute coords, perimeter.
// Block 0 additionally writes mass and height rows.
// ---------------------------------------------------------------------------
__global__ __launch_bounds__(256) void final_kernel(
    const float* __restrict__ tris, int F,
    const float* __restrict__ htbc, const float* __restrict__ lhbc,
    const float* __restrict__ bc0, const float* __restrict__ bc1,
    const float* __restrict__ bc2,
    const int* __restrict__ hti, const int* __restrict__ lhi,
    const int* __restrict__ fi0, const int* __restrict__ fi1,
    const int* __restrict__ fi2,
    const unsigned long long* __restrict__ best,
    const float* __restrict__ mass_acc,
    float* __restrict__ out) {
    int pair = blockIdx.x;  // 0..11
    int m = pair >> 2, b = pair & 3;

    if (pair == 0) {
        if (threadIdx.x >= 64 && threadIdx.x < 68) {
            int bb = threadIdx.x - 64;
            out[bb] = fabsf(mass_acc[bb]) / 6.0f * 985.0f;
        }
        if (threadIdx.x >= 96 && threadIdx.x < 100) {
            int bb = threadIdx.x - 96;
            int hf = hti[0], lf = lhi[0];
            const float* th = tris + ((size_t)(bb * F + hf)) * 9;
            const float* tl = tris + ((size_t)(bb * F + lf)) * 9;
            float hy = htbc[0] * th[1] + htbc[1] * th[4] + htbc[2] * th[7];
            float ly = lhbc[0] * tl[1] + lhbc[1] * tl[4] + lhbc[2] * tl[7];
            out[4 + bb] = fabsf(hy - ly);
        }
    }

    const float* bc = (m == 0) ? bc0 : ((m == 1) ? bc1 : bc2);
    int fidx = (m == 0) ? fi0[0] : ((m == 1) ? fi1[0] : fi2[0]);
    const float* vt = tris + ((size_t)(b * F + fidx)) * 9;
    float h = bc[0] * vt[1] + bc[1] * vt[4] + bc[2] * vt[7];

    __shared__ float ex[NUM_DIRS], ez[NUM_DIRS];
    for (int d = threadIdx.x; d < NUM_DIRS; d += blockDim.x) {
        unsigned long long e = best[pair * NUM_DIRS + d];
        unsigned int idx =
            (e == 0ull) ? 0u
                        : (0xFFFFFFFFu - (unsigned int)(e & 0xFFFFFFFFull));
        int f = (int)(idx / 3u);
        int k = (int)(idx - (unsigned int)f * 3u);
        int j = (k == 2) ? 0 : (k + 1);
        const float* t = tris + ((size_t)(b * F + f)) * 9;
        float yi = t[k * 3 + 1], yj = t[j * 3 + 1];
        float denom = yj - yi;
        float safe = (fabsf(denom) > 1e-12f) ? denom : 1e-12f;
        float tt = fminf(fmaxf((h - yi) / safe, 0.f), 1.f);
        ex[d] = t[k * 3 + 0] + tt * (t[j * 3 + 0] - t[k * 3 + 0]);
        ez[d] = t[k * 3 + 2] + tt * (t[j * 3 + 2] - t[k * 3 + 2]);
    }
    __syncthreads();

    float local = 0.f;
    for (int d = threadIdx.x; d < NUM_DIRS; d += blockDim.x) {
        int d1 = (d + 1) % NUM_DIRS;
        float dx = ex[d] - ex[d1];
        float dz = ez[d] - ez[d1];
        local += sqrtf(dx * dx + dz * dz + 1e-20f);
    }
    for (int off = 32; off; off >>= 1) local += __shfl_down(local, off, 64);
    __shared__ float wsum[4];
    int lane = threadIdx.x & 63, w = threadIdx.x >> 6;
    if (lane == 0) wsum[w] = local;
    __syncthreads();
    if (threadIdx.x == 0)
        out[(2 + m) * 4 + b] = wsum[0] + wsum[1] + wsum[2] + wsum[3];
}

// ---------------------------------------------------------------------------
extern "C" void kernel_launch(void* const* d_in, const int* in_sizes, int n_in,
                              void* d_out, int out_size, void* d_ws,
                              size_t ws_size, hipStream_t stream) {
    const float* tris = (const float*)d_in[0];
    const float* htbc = (const float*)d_in[1];
    const float* lhbc = (const float*)d_in[2];
    const float* cbc  = (const float*)d_in[3];
    const float* bbc  = (const float*)d_in[4];
    const float* hbc  = (const float*)d_in[5];
    const int* hti = (const int*)d_in[6];
    const int* lhi = (const int*)d_in[7];
    const int* cfi = (const int*)d_in[8];
    const int* bfi = (const int*)d_in[9];
    const int* hfi = (const int*)d_in[10];
    float* out = (float*)d_out;

    int F = in_sizes[0] / 36;  // B=4, 3 verts, 3 coords

    unsigned long long* best = (unsigned long long*)d_ws;
    float* mass_acc =
        (float*)((char*)d_ws + (size_t)NPAIRS * NUM_DIRS * sizeof(unsigned long long));

    // zero best[] (packed argmax sentinels) and mass accumulators
    hipMemsetAsync(d_ws, 0,
                   (size_t)NPAIRS * NUM_DIRS * sizeof(unsigned long long) +
                       4 * sizeof(float),
                   stream);

    dim3 gA(16, 4);
    mass_kernel<<<gA, 256, 0, stream>>>(tris, F, mass_acc);

    int nChunks = (F + CF - 1) / CF;
    dim3 gB(nChunks, NPAIRS);
    scan_kernel<<<gB, 256, 0, stream>>>(tris, F, cbc, bbc, hbc, cfi, bfi, hfi,
                                        best);

    final_kernel<<<NPAIRS, 256, 0, stream>>>(tris, F, htbc, lhbc, cbc, bbc,
                                             hbc, hti, lhi, cfi, bfi, hfi,
                                             best, mass_acc, out);
}

// Round 2
// 56.443 us; speedup vs baseline: 1.1138x; 1.1138x over previous
//
#include <hip/hip_runtime.h>
#include <math.h>

#define NUM_DIRS 720
#define CF 512            // faces per chunk
#define NPAIRS 12         // 3 measurements x 4 batches
#define KC 64             // coarse directions
#define SCAP 16384        // survivor capacity per pair
#define NC4 6             // argmax survivor chunks

// orderable-uint transform for float atomicMax
__device__ __forceinline__ unsigned int ordf(float f) {
    unsigned int b = __float_as_uint(f);
    return (b & 0x80000000u) ? ~b : (b | 0x80000000u);
}
__device__ __forceinline__ float unordf(unsigned int u) {
    unsigned int b = (u & 0x80000000u) ? (u ^ 0x80000000u) : ~u;
    return __uint_as_float(b);
}

// plane height for measurement: identical code in all kernels
__device__ __forceinline__ float plane_h(const float* __restrict__ tris, int F,
                                         int b, int fidx,
                                         const float* __restrict__ bc) {
    const float* vt = tris + ((size_t)(b * F + fidx)) * 9;
    return fmaf(bc[2], vt[7], fmaf(bc[1], vt[4], bc[0] * vt[1]));
}

// edge-plane crossing; identical arithmetic to the reference
__device__ __forceinline__ bool crossing(const float* __restrict__ v, int k,
                                         float h, float& px, float& pz) {
    int j = (k == 2) ? 0 : (k + 1);
    float yi = v[k * 3 + 1], yj = v[j * 3 + 1];
    if (!((yi - h) * (yj - h) < 0.f)) return false;
    float denom = yj - yi;
    float safe = (fabsf(denom) > 1e-12f) ? denom : 1e-12f;
    float tt = fminf(fmaxf((h - yi) / safe, 0.f), 1.f);
    px = v[k * 3 + 0] + tt * (v[j * 3 + 0] - v[k * 3 + 0]);
    pz = v[k * 3 + 2] + tt * (v[j * 3 + 2] - v[k * 3 + 2]);
    return true;
}

// ---------------------------------------------------------------------------
// Kernel A: mass partial sums.
// ---------------------------------------------------------------------------
__global__ __launch_bounds__(256) void mass_kernel(const float* __restrict__ tris,
                                                   int F,
                                                   float* __restrict__ mass_acc) {
    int b = blockIdx.y;
    float local = 0.f;
    for (int f = blockIdx.x * blockDim.x + threadIdx.x; f < F;
         f += gridDim.x * blockDim.x) {
        const float* t = tris + ((size_t)(b * F + f)) * 9;
        float x0 = t[0], y0 = t[1], z0 = t[2];
        float x1 = t[3], y1 = t[4], z1 = t[5];
        float x2 = t[6], y2 = t[7], z2 = t[8];
        local += -x2 * y1 * z0 + x1 * y2 * z0 + x2 * y0 * z1
                 - x0 * y2 * z1 - x1 * y0 * z2 + x0 * y1 * z2;
    }
    for (int off = 32; off; off >>= 1) local += __shfl_down(local, off, 64);
    __shared__ float wsum[4];
    int lane = threadIdx.x & 63, w = threadIdx.x >> 6;
    if (lane == 0) wsum[w] = local;
    __syncthreads();
    if (threadIdx.x == 0)
        atomicAdd(&mass_acc[b], wsum[0] + wsum[1] + wsum[2] + wsum[3]);
}

// ---------------------------------------------------------------------------
// Kernel B: coarse supports.  Compact chunk's crossings to LDS, then value-only
// max over KC coarse dirs (thread t: dir t&63, point-slice t>>6) + max radius.
// ---------------------------------------------------------------------------
__global__ __launch_bounds__(256) void coarse_kernel(
    const float* __restrict__ tris, int F,
    const float* __restrict__ bc0, const float* __restrict__ bc1,
    const float* __restrict__ bc2,
    const int* __restrict__ fi0, const int* __restrict__ fi1,
    const int* __restrict__ fi2,
    unsigned int* __restrict__ M32, unsigned int* __restrict__ R2) {
    int pair = blockIdx.y;
    int m = pair >> 2, b = pair & 3;
    const float* bc = (m == 0) ? bc0 : ((m == 1) ? bc1 : bc2);
    int fidx = (m == 0) ? fi0[0] : ((m == 1) ? fi1[0] : fi2[0]);
    float h = plane_h(tris, F, b, fidx, bc);

    __shared__ float2 sp[3 * CF];
    __shared__ unsigned int sM[KC];
    __shared__ int cnt;
    if (threadIdx.x < KC) sM[threadIdx.x] = 0;
    if (threadIdx.x == 0) cnt = 0;
    __syncthreads();

    float r2max = 0.f;
    int f0 = blockIdx.x * CF;
    int fend = min(f0 + CF, F);
    for (int f = f0 + threadIdx.x; f < fend; f += blockDim.x) {
        const float* t = tris + ((size_t)(b * F + f)) * 9;
        float v[9];
#pragma unroll
        for (int i = 0; i < 9; i++) v[i] = t[i];
#pragma unroll
        for (int k = 0; k < 3; k++) {
            float px, pz;
            if (crossing(v, k, h, px, pz)) {
                int n = atomicAdd(&cnt, 1);
                sp[n] = make_float2(px, pz);
                r2max = fmaxf(r2max, px * px + pz * pz);
            }
        }
    }
    // radius: wave reduce, one global atomic per wave (bits of non-neg float
    // are order-preserving)
    for (int off = 32; off; off >>= 1)
        r2max = fmaxf(r2max, __shfl_down(r2max, off, 64));
    if ((threadIdx.x & 63) == 0)
        atomicMax(&R2[pair], __float_as_uint(r2max));

    __syncthreads();
    int n = cnt;
    int d = threadIdx.x & (KC - 1);
    int slice = threadIdx.x >> 6;  // 0..3
    float th = (float)d * (float)(6.283185307179586 / KC);
    float s, c;
    sincosf(th, &s, &c);
    float mv = -INFINITY;
    for (int i = slice; i < n; i += 4) {
        float2 p = sp[i];
        mv = fmaxf(mv, fmaf(p.x, c, p.y * s));
    }
    atomicMax(&sM[d], ordf(mv));
    __syncthreads();
    if (threadIdx.x < KC) atomicMax(&M32[pair * KC + threadIdx.x], sM[threadIdx.x]);
}

// ---------------------------------------------------------------------------
// Kernel C: survivors.  tau = min_k M_k - 0.052*R (valid support lower bound
// over ALL fine dirs: support is R-Lipschitz, max angle to nearest coarse dir
// is pi/64 -> slack R*2*sin(pi/128)*1.05 < 0.052R).  Keep points with r>=tau.
// ---------------------------------------------------------------------------
__global__ __launch_bounds__(256) void surv_kernel(
    const float* __restrict__ tris, int F,
    const float* __restrict__ bc0, const float* __restrict__ bc1,
    const float* __restrict__ bc2,
    const int* __restrict__ fi0, const int* __restrict__ fi1,
    const int* __restrict__ fi2,
    const unsigned int* __restrict__ M32, const unsigned int* __restrict__ R2,
    int* __restrict__ scnt, float2* __restrict__ slist) {
    int pair = blockIdx.y;
    int m = pair >> 2, b = pair & 3;
    const float* bc = (m == 0) ? bc0 : ((m == 1) ? bc1 : bc2);
    int fidx = (m == 0) ? fi0[0] : ((m == 1) ? fi1[0] : fi2[0]);
    float h = plane_h(tris, F, b, fidx, bc);

    __shared__ float tau_s;
    if (threadIdx.x == 0) {
        unsigned int mm = 0xFFFFFFFFu;
        for (int k = 0; k < KC; k++) mm = min(mm, M32[pair * KC + k]);
        float minM = unordf(mm);
        float R = sqrtf(__uint_as_float(R2[pair]));
        tau_s = minM - 0.052f * R;
    }
    __syncthreads();
    float tau = tau_s;
    bool useTau = (tau > 0.f);
    float tau2 = tau * tau;

    int f0 = blockIdx.x * CF;
    int fend = min(f0 + CF, F);
    for (int f = f0 + threadIdx.x; f < fend; f += blockDim.x) {
        const float* t = tris + ((size_t)(b * F + f)) * 9;
        float v[9];
#pragma unroll
        for (int i = 0; i < 9; i++) v[i] = t[i];
#pragma unroll
        for (int k = 0; k < 3; k++) {
            float px, pz;
            if (crossing(v, k, h, px, pz)) {
                float r2 = px * px + pz * pz;
                if (!useTau || r2 >= tau2) {
                    int idx = atomicAdd(&scnt[pair], 1);
                    if (idx < SCAP) slist[pair * SCAP + idx] = make_float2(px, pz);
                }
            }
        }
    }
}

// ---------------------------------------------------------------------------
// Kernel D: exact 720-dir argmax over survivors (winners are survivors by
// construction).  Packed u64 atomicMax merge across chunks.
// ---------------------------------------------------------------------------
__global__ __launch_bounds__(256) void amax_kernel(
    const int* __restrict__ scnt, const float2* __restrict__ slist,
    unsigned long long* __restrict__ best) {
    int pair = blockIdx.y;
    int chunk = blockIdx.x;
    int ns = min(scnt[pair], SCAP);
    if (ns == 0) return;
    int cs = (ns + NC4 - 1) / NC4;
    int i0 = chunk * cs;
    int i1 = min(i0 + cs, ns);
    if (i0 >= i1) return;
    int nn = i1 - i0;

    __shared__ float2 sp[(SCAP + NC4 - 1) / NC4 + 8];
    for (int i = threadIdx.x; i < nn; i += blockDim.x)
        sp[i] = slist[pair * SCAP + i0 + i];
    __syncthreads();

    const float dth = (float)(6.283185307179586 / NUM_DIRS);
    int d0 = threadIdx.x, d1 = threadIdx.x + 256, d2 = threadIdx.x + 512;
    float c0, s0, c1, s1, c2 = 0.f, s2 = 0.f;
    sincosf((float)d0 * dth, &s0, &c0);
    sincosf((float)d1 * dth, &s1, &c1);
    if (d2 < NUM_DIRS) sincosf((float)d2 * dth, &s2, &c2);

    float bp0 = -INFINITY, bp1 = -INFINITY, bp2 = -INFINITY;
    int bs0 = 0, bs1 = 0, bs2 = 0;
    for (int i = 0; i < nn; i++) {
        float2 p = sp[i];
        float q0 = fmaf(p.x, c0, p.y * s0);
        float q1 = fmaf(p.x, c1, p.y * s1);
        float q2 = fmaf(p.x, c2, p.y * s2);
        if (q0 > bp0) { bp0 = q0; bs0 = i; }
        if (q1 > bp1) { bp1 = q1; bs1 = i; }
        if (q2 > bp2) { bp2 = q2; bs2 = i; }
    }
#pragma unroll
    for (int q = 0; q < 3; q++) {
        int d = (q == 0) ? d0 : ((q == 1) ? d1 : d2);
        if (d >= NUM_DIRS) continue;
        float bp = (q == 0) ? bp0 : ((q == 1) ? bp1 : bp2);
        int bs = (q == 0) ? bs0 : ((q == 1) ? bs1 : bs2);
        unsigned int gidx = (unsigned int)(i0 + bs);
        unsigned long long e = ((unsigned long long)ordf(bp) << 32) |
                               (unsigned long long)(0xFFFFFFFFu - gidx);
        atomicMax(&best[pair * NUM_DIRS + d], e);
    }
}

// ---------------------------------------------------------------------------
// Kernel E: finalize.  Winner coords from slist, perimeter; mass+height too.
// ---------------------------------------------------------------------------
__global__ __launch_bounds__(256) void final_kernel(
    const float* __restrict__ tris, int F,
    const float* __restrict__ htbc, const float* __restrict__ lhbc,
    const int* __restrict__ hti, const int* __restrict__ lhi,
    const unsigned long long* __restrict__ best,
    const float2* __restrict__ slist,
    const float* __restrict__ mass_acc,
    float* __restrict__ out) {
    int pair = blockIdx.x;  // 0..11
    int m = pair >> 2, b = pair & 3;

    if (pair == 0) {
        if (threadIdx.x >= 64 && threadIdx.x < 68) {
            int bb = threadIdx.x - 64;
            out[bb] = fabsf(mass_acc[bb]) / 6.0f * 985.0f;
        }
        if (threadIdx.x >= 96 && threadIdx.x < 100) {
            int bb = threadIdx.x - 96;
            float hy = plane_h(tris, F, bb, hti[0], htbc);
            float ly = plane_h(tris, F, bb, lhi[0], lhbc);
            out[4 + bb] = fabsf(hy - ly);
        }
    }

    __shared__ float ex[NUM_DIRS], ez[NUM_DIRS];
    for (int d = threadIdx.x; d < NUM_DIRS; d += blockDim.x) {
        unsigned long long e = best[pair * NUM_DIRS + d];
        unsigned int idx = 0xFFFFFFFFu - (unsigned int)(e & 0xFFFFFFFFull);
        if (e == 0ull) idx = 0u;
        if (idx >= SCAP) idx = SCAP - 1;
        float2 p = slist[pair * SCAP + idx];
        ex[d] = p.x;
        ez[d] = p.y;
    }
    __syncthreads();

    float local = 0.f;
    for (int d = threadIdx.x; d < NUM_DIRS; d += blockDim.x) {
        int d1 = (d + 1) % NUM_DIRS;
        float dx = ex[d] - ex[d1];
        float dz = ez[d] - ez[d1];
        local += sqrtf(dx * dx + dz * dz + 1e-20f);
    }
    for (int off = 32; off; off >>= 1) local += __shfl_down(local, off, 64);
    __shared__ float wsum[4];
    int lane = threadIdx.x & 63, w = threadIdx.x >> 6;
    if (lane == 0) wsum[w] = local;
    __syncthreads();
    if (threadIdx.x == 0)
        out[(2 + m) * 4 + b] = wsum[0] + wsum[1] + wsum[2] + wsum[3];
}

// ---------------------------------------------------------------------------
extern "C" void kernel_launch(void* const* d_in, const int* in_sizes, int n_in,
                              void* d_out, int out_size, void* d_ws,
                              size_t ws_size, hipStream_t stream) {
    const float* tris = (const float*)d_in[0];
    const float* htbc = (const float*)d_in[1];
    const float* lhbc = (const float*)d_in[2];
    const float* cbc  = (const float*)d_in[3];
    const float* bbc  = (const float*)d_in[4];
    const float* hbc  = (const float*)d_in[5];
    const int* hti = (const int*)d_in[6];
    const int* lhi = (const int*)d_in[7];
    const int* cfi = (const int*)d_in[8];
    const int* bfi = (const int*)d_in[9];
    const int* hfi = (const int*)d_in[10];
    float* out = (float*)d_out;

    int F = in_sizes[0] / 36;

    // workspace layout
    char* w = (char*)d_ws;
    unsigned long long* best = (unsigned long long*)w;             // 12*720*8 = 69120
    unsigned int* M32 = (unsigned int*)(w + 69120);                // 12*64*4  = 3072
    unsigned int* R2  = (unsigned int*)(w + 72192);                // 12*4     = 48
    int* scnt         = (int*)(w + 72240);                         // 12*4     = 48
    float* mass_acc   = (float*)(w + 72288);                       // 16
    float2* slist     = (float2*)(w + 73728);                      // 12*16384*8 = 1.5MB

    hipMemsetAsync(d_ws, 0, 72304, stream);

    dim3 gA(16, 4);
    mass_kernel<<<gA, 256, 0, stream>>>(tris, F, mass_acc);

    int nChunks = (F + CF - 1) / CF;
    dim3 gB(nChunks, NPAIRS);
    coarse_kernel<<<gB, 256, 0, stream>>>(tris, F, cbc, bbc, hbc, cfi, bfi,
                                          hfi, M32, R2);
    surv_kernel<<<gB, 256, 0, stream>>>(tris, F, cbc, bbc, hbc, cfi, bfi, hfi,
                                        M32, R2, scnt, slist);
    dim3 gD(NC4, NPAIRS);
    amax_kernel<<<gD, 256, 0, stream>>>(scnt, slist, best);

    final_kernel<<<NPAIRS, 256, 0, stream>>>(tris, F, htbc, lhbc, hti, lhi,
                                             best, slist, mass_acc, out);
}

// Round 3
// 50.209 us; speedup vs baseline: 1.2521x; 1.1242x over previous
//
#include <hip/hip_runtime.h>
#include <math.h>

#define NUM_DIRS 720
#define CF 512              // faces per chunk
#define SCHUNK (3 * CF)     // max crossings per chunk (capacity, can't overflow)
#define NPAIRS 12           // 3 measurements x 4 batches
#define KC 64               // coarse directions
#define NCHMAX 64           // max chunks supported
#define LDSCAP 4096         // survivors staged in LDS in final kernel

// orderable-uint transform for float max in integer space
__device__ __forceinline__ unsigned int ordf(float f) {
    unsigned int b = __float_as_uint(f);
    return (b & 0x80000000u) ? ~b : (b | 0x80000000u);
}
__device__ __forceinline__ float unordf(unsigned int u) {
    unsigned int b = (u & 0x80000000u) ? (u ^ 0x80000000u) : ~u;
    return __uint_as_float(b);
}

__device__ __forceinline__ float plane_h(const float* __restrict__ tris, int F,
                                         int b, int fidx,
                                         const float* __restrict__ bc) {
    const float* vt = tris + ((size_t)(b * F + fidx)) * 9;
    return fmaf(bc[2], vt[7], fmaf(bc[1], vt[4], bc[0] * vt[1]));
}

// edge-plane crossing; identical arithmetic to the reference
__device__ __forceinline__ bool crossing(const float* __restrict__ v, int k,
                                         float h, float& px, float& pz) {
    int j = (k == 2) ? 0 : (k + 1);
    float yi = v[k * 3 + 1], yj = v[j * 3 + 1];
    if (!((yi - h) * (yj - h) < 0.f)) return false;
    float denom = yj - yi;
    float safe = (fabsf(denom) > 1e-12f) ? denom : 1e-12f;
    float tt = fminf(fmaxf((h - yi) / safe, 0.f), 1.f);
    px = v[k * 3 + 0] + tt * (v[j * 3 + 0] - v[k * 3 + 0]);
    pz = v[k * 3 + 2] + tt * (v[j * 3 + 2] - v[k * 3 + 2]);
    return true;
}

// ---------------------------------------------------------------------------
// K1: coarse supports (+ mass partials for m==0 blocks).
// grid = (NCH, 12).  All global writes are per-(pair,chunk) owned slots.
// ---------------------------------------------------------------------------
__global__ __launch_bounds__(256) void coarse_kernel(
    const float* __restrict__ tris, int F, int NCH,
    const float* __restrict__ bc0, const float* __restrict__ bc1,
    const float* __restrict__ bc2,
    const int* __restrict__ fi0, const int* __restrict__ fi1,
    const int* __restrict__ fi2,
    unsigned int* __restrict__ M_part, float* __restrict__ R2_part,
    float* __restrict__ mass_part) {
    int pair = blockIdx.y, chunk = blockIdx.x;
    int m = pair >> 2, b = pair & 3;
    const float* bc = (m == 0) ? bc0 : ((m == 1) ? bc1 : bc2);
    int fidx = (m == 0) ? fi0[0] : ((m == 1) ? fi1[0] : fi2[0]);
    float h = plane_h(tris, F, b, fidx, bc);

    __shared__ float2 sp[SCHUNK];
    __shared__ unsigned int sM[KC];
    __shared__ int cnt;
    __shared__ float redA[4], redB[4];
    if (threadIdx.x < KC) sM[threadIdx.x] = 0;
    if (threadIdx.x == 0) cnt = 0;
    __syncthreads();

    float r2max = 0.f, msum = 0.f;
    int f0 = chunk * CF, fend = min(f0 + CF, F);
    for (int f = f0 + threadIdx.x; f < fend; f += blockDim.x) {
        const float* t = tris + ((size_t)(b * F + f)) * 9;
        float v[9];
#pragma unroll
        for (int i = 0; i < 9; i++) v[i] = t[i];
        if (m == 0) {
            msum += -v[6] * v[4] * v[2] + v[3] * v[7] * v[2]
                    + v[6] * v[1] * v[5] - v[0] * v[7] * v[5]
                    - v[3] * v[1] * v[8] + v[0] * v[4] * v[8];
        }
#pragma unroll
        for (int k = 0; k < 3; k++) {
            float px, pz;
            if (crossing(v, k, h, px, pz)) {
                int n = atomicAdd(&cnt, 1);
                sp[n] = make_float2(px, pz);
                r2max = fmaxf(r2max, px * px + pz * pz);
            }
        }
    }
    int lane = threadIdx.x & 63, w = threadIdx.x >> 6;
    for (int off = 32; off; off >>= 1)
        r2max = fmaxf(r2max, __shfl_down(r2max, off, 64));
    if (lane == 0) redA[w] = r2max;
    if (m == 0) {
        for (int off = 32; off; off >>= 1) msum += __shfl_down(msum, off, 64);
        if (lane == 0) redB[w] = msum;
    }
    __syncthreads();
    if (threadIdx.x == 0) {
        R2_part[pair * NCH + chunk] =
            fmaxf(fmaxf(redA[0], redA[1]), fmaxf(redA[2], redA[3]));
        if (m == 0)
            mass_part[b * NCH + chunk] = redB[0] + redB[1] + redB[2] + redB[3];
    }

    int n = cnt;
    int d = threadIdx.x & (KC - 1);
    int slice = threadIdx.x >> 6;  // 0..3
    float s, c;
    sincosf((float)d * (float)(6.283185307179586 / KC), &s, &c);
    float mv = -INFINITY;
    for (int i = slice; i < n; i += 4) {
        float2 p = sp[i];
        mv = fmaxf(mv, fmaf(p.x, c, p.y * s));
    }
    atomicMax(&sM[d], ordf(mv));
    __syncthreads();
    if (threadIdx.x < KC)
        M_part[(pair * NCH + chunk) * KC + threadIdx.x] = sM[threadIdx.x];
}

// ---------------------------------------------------------------------------
// K2: survivors.  tau = min_d(max_c M) - 0.052*R (support is R-Lipschitz in
// direction; max angular gap to a coarse dir is pi/64 -> slack < 0.052R).
// Survivors go to per-(pair,chunk) private segments: no cross-block atomics.
// ---------------------------------------------------------------------------
__global__ __launch_bounds__(256) void surv_kernel(
    const float* __restrict__ tris, int F, int NCH,
    const float* __restrict__ bc0, const float* __restrict__ bc1,
    const float* __restrict__ bc2,
    const int* __restrict__ fi0, const int* __restrict__ fi1,
    const int* __restrict__ fi2,
    const unsigned int* __restrict__ M_part,
    const float* __restrict__ R2_part,
    int* __restrict__ cnt_part, float2* __restrict__ slist) {
    int pair = blockIdx.y, chunk = blockIdx.x;
    int m = pair >> 2, b = pair & 3;
    const float* bc = (m == 0) ? bc0 : ((m == 1) ? bc1 : bc2);
    int fidx = (m == 0) ? fi0[0] : ((m == 1) ? fi1[0] : fi2[0]);
    float h = plane_h(tris, F, b, fidx, bc);

    __shared__ float minM_s, rmax_s;
    __shared__ int cnt;
    int tid = threadIdx.x;
    if (tid < 64) {
        unsigned int mx = 0;
        for (int c = 0; c < NCH; c++)
            mx = max(mx, M_part[(pair * NCH + c) * KC + tid]);
        float Md = unordf(mx);
        for (int off = 32; off; off >>= 1)
            Md = fminf(Md, __shfl_down(Md, off, 64));
        if (tid == 0) minM_s = Md;
    } else if (tid < 128) {
        int c = tid - 64;
        float r2 = (c < NCH) ? R2_part[pair * NCH + c] : 0.f;
        for (int off = 32; off; off >>= 1)
            r2 = fmaxf(r2, __shfl_down(r2, off, 64));
        if (tid == 64) rmax_s = r2;
    }
    if (tid == 0) cnt = 0;
    __syncthreads();
    float tau = minM_s - 0.052f * sqrtf(rmax_s);
    bool useTau = (tau > 0.f);
    float tau2 = tau * tau;

    float2* seg = slist + (size_t)(pair * NCH + chunk) * SCHUNK;
    int f0 = chunk * CF, fend = min(f0 + CF, F);
    for (int f = f0 + tid; f < fend; f += blockDim.x) {
        const float* t = tris + ((size_t)(b * F + f)) * 9;
        float v[9];
#pragma unroll
        for (int i = 0; i < 9; i++) v[i] = t[i];
#pragma unroll
        for (int k = 0; k < 3; k++) {
            float px, pz;
            if (crossing(v, k, h, px, pz)) {
                float r2 = px * px + pz * pz;
                if (!useTau || r2 >= tau2) {
                    int idx = atomicAdd(&cnt, 1);
                    seg[idx] = make_float2(px, pz);
                }
            }
        }
    }
    __syncthreads();
    if (tid == 0) cnt_part[pair * NCH + chunk] = cnt;
}

// ---------------------------------------------------------------------------
// K3: final.  Per-pair block: gather survivors -> LDS, exact 720-dir argmax
// tracking winner COORDS in registers, perimeter reduce.  Block 0 also
// writes mass and height.
// ---------------------------------------------------------------------------
__global__ __launch_bounds__(256) void final_kernel(
    const float* __restrict__ tris, int F, int NCH,
    const float* __restrict__ htbc, const float* __restrict__ lhbc,
    const int* __restrict__ hti, const int* __restrict__ lhi,
    const int* __restrict__ cnt_part, const float2* __restrict__ slist,
    const float* __restrict__ mass_part, float* __restrict__ out) {
    int pair = blockIdx.x;  // 0..11
    int m = pair >> 2, b = pair & 3;
    int tid = threadIdx.x;

    if (pair == 0) {
        if (tid >= 64 && tid < 68) {
            int bb = tid - 64;
            float s = 0.f;
            for (int c = 0; c < NCH; c++) s += mass_part[bb * NCH + c];
            out[bb] = fabsf(s) / 6.0f * 985.0f;
        }
        if (tid >= 96 && tid < 100) {
            int bb = tid - 96;
            float hy = plane_h(tris, F, bb, hti[0], htbc);
            float ly = plane_h(tris, F, bb, lhi[0], lhbc);
            out[4 + bb] = fabsf(hy - ly);
        }
    }

    __shared__ int soff[NCHMAX + 1];
    __shared__ float2 sp[LDSCAP];
    __shared__ float ex[NUM_DIRS], ez[NUM_DIRS];
    __shared__ float wsum[4];

    if (tid == 0) {
        int acc = 0;
        soff[0] = 0;
        for (int c = 0; c < NCH; c++) {
            acc += cnt_part[pair * NCH + c];
            soff[c + 1] = acc;
        }
    }
    __syncthreads();
    int ns = soff[NCH];

    for (int c = 0; c < NCH; c++) {
        int base = soff[c], nc = soff[c + 1] - base;
        const float2* seg = slist + (size_t)(pair * NCH + c) * SCHUNK;
        for (int i = tid; i < nc; i += 256) {
            int g = base + i;
            if (g < LDSCAP) sp[g] = seg[i];
        }
    }
    __syncthreads();

    const float dth = (float)(6.283185307179586 / NUM_DIRS);
    int d0 = tid, d1 = tid + 256, d2 = tid + 512;
    float c0, s0, c1, s1, c2 = 0.f, s2 = 0.f;
    sincosf((float)d0 * dth, &s0, &c0);
    sincosf((float)d1 * dth, &s1, &c1);
    if (d2 < NUM_DIRS) sincosf((float)d2 * dth, &s2, &c2);

    float bp0 = -INFINITY, bp1 = -INFINITY, bp2 = -INFINITY;
    float bx0 = 0.f, bz0 = 0.f, bx1 = 0.f, bz1 = 0.f, bx2 = 0.f, bz2 = 0.f;
    int nl = min(ns, LDSCAP);
    for (int i = 0; i < nl; i++) {
        float2 p = sp[i];
        float q0 = fmaf(p.x, c0, p.y * s0);
        float q1 = fmaf(p.x, c1, p.y * s1);
        float q2 = fmaf(p.x, c2, p.y * s2);
        if (q0 > bp0) { bp0 = q0; bx0 = p.x; bz0 = p.y; }
        if (q1 > bp1) { bp1 = q1; bx1 = p.x; bz1 = p.y; }
        if (q2 > bp2) { bp2 = q2; bx2 = p.x; bz2 = p.y; }
    }
    if (ns > LDSCAP) {  // degenerate fallback; never taken with this data
        for (int c = 0; c < NCH; c++) {
            int base = soff[c], e = soff[c + 1];
            const float2* seg = slist + (size_t)(pair * NCH + c) * SCHUNK;
            for (int g = max(base, LDSCAP); g < e; g++) {
                float2 p = seg[g - base];
                float q0 = fmaf(p.x, c0, p.y * s0);
                float q1 = fmaf(p.x, c1, p.y * s1);
                float q2 = fmaf(p.x, c2, p.y * s2);
                if (q0 > bp0) { bp0 = q0; bx0 = p.x; bz0 = p.y; }
                if (q1 > bp1) { bp1 = q1; bx1 = p.x; bz1 = p.y; }
                if (q2 > bp2) { bp2 = q2; bx2 = p.x; bz2 = p.y; }
            }
        }
    }
    ex[d0] = bx0; ez[d0] = bz0;
    ex[d1] = bx1; ez[d1] = bz1;
    if (d2 < NUM_DIRS) { ex[d2] = bx2; ez[d2] = bz2; }
    __syncthreads();

    float local = 0.f;
    for (int d = tid; d < NUM_DIRS; d += 256) {
        int dn = (d + 1) % NUM_DIRS;
        float dx = ex[d] - ex[dn];
        float dz = ez[d] - ez[dn];
        local += sqrtf(dx * dx + dz * dz + 1e-20f);
    }
    int lane = tid & 63, w = tid >> 6;
    for (int off = 32; off; off >>= 1) local += __shfl_down(local, off, 64);
    if (lane == 0) wsum[w] = local;
    __syncthreads();
    if (tid == 0)
        out[(2 + m) * 4 + b] = wsum[0] + wsum[1] + wsum[2] + wsum[3];
}

// ---------------------------------------------------------------------------
extern "C" void kernel_launch(void* const* d_in, const int* in_sizes, int n_in,
                              void* d_out, int out_size, void* d_ws,
                              size_t ws_size, hipStream_t stream) {
    const float* tris = (const float*)d_in[0];
    const float* htbc = (const float*)d_in[1];
    const float* lhbc = (const float*)d_in[2];
    const float* cbc  = (const float*)d_in[3];
    const float* bbc  = (const float*)d_in[4];
    const float* hbc  = (const float*)d_in[5];
    const int* hti = (const int*)d_in[6];
    const int* lhi = (const int*)d_in[7];
    const int* cfi = (const int*)d_in[8];
    const int* bfi = (const int*)d_in[9];
    const int* hfi = (const int*)d_in[10];
    float* out = (float*)d_out;

    int F = in_sizes[0] / 36;
    int NCH = (F + CF - 1) / CF;  // 41 for F=20908 (<= NCHMAX)

    // workspace layout: all owned slots, nothing needs pre-zeroing
    char* w = (char*)d_ws;
    size_t off = 0;
    unsigned int* M_part = (unsigned int*)(w + off);
    off += (size_t)NPAIRS * NCH * KC * sizeof(unsigned int);
    float* R2_part = (float*)(w + off);
    off += (size_t)NPAIRS * NCH * sizeof(float);
    int* cnt_part = (int*)(w + off);
    off += (size_t)NPAIRS * NCH * sizeof(int);
    float* mass_part = (float*)(w + off);
    off += (size_t)4 * NCH * sizeof(float);
    off = (off + 255) & ~(size_t)255;
    float2* slist = (float2*)(w + off);

    dim3 g(NCH, NPAIRS);
    coarse_kernel<<<g, 256, 0, stream>>>(tris, F, NCH, cbc, bbc, hbc, cfi,
                                         bfi, hfi, M_part, R2_part, mass_part);
    surv_kernel<<<g, 256, 0, stream>>>(tris, F, NCH, cbc, bbc, hbc, cfi, bfi,
                                       hfi, M_part, R2_part, cnt_part, slist);
    final_kernel<<<NPAIRS, 256, 0, stream>>>(tris, F, NCH, htbc, lhbc, hti,
                                             lhi, cnt_part, slist, mass_part,
                                             out);
}

// Round 4
// 42.481 us; speedup vs baseline: 1.4799x; 1.1819x over previous
//
#include <hip/hip_runtime.h>
#include <math.h>

#define NUM_DIRS 720
#define CF 1024             // faces per chunk
#define SCHUNK (3 * CF)     // max crossings per chunk
#define NPAIRS 12           // 3 measurements x 4 batches
#define KC 64               // coarse directions
#define NCHMAX 64           // max chunks supported
#define LDSCAP 3072         // survivors staged in LDS in final kernel

// orderable-uint transform for float max in integer space
__device__ __forceinline__ unsigned int ordf(float f) {
    unsigned int b = __float_as_uint(f);
    return (b & 0x80000000u) ? ~b : (b | 0x80000000u);
}
__device__ __forceinline__ float unordf(unsigned int u) {
    unsigned int b = (u & 0x80000000u) ? (u ^ 0x80000000u) : ~u;
    return __uint_as_float(b);
}

__device__ __forceinline__ float plane_h(const float* __restrict__ tris, int F,
                                         int b, int fidx,
                                         const float* __restrict__ bc) {
    const float* vt = tris + ((size_t)(b * F + fidx)) * 9;
    return fmaf(bc[2], vt[7], fmaf(bc[1], vt[4], bc[0] * vt[1]));
}

// edge-plane crossing; identical arithmetic to the reference
__device__ __forceinline__ bool crossing(const float* __restrict__ v, int k,
                                         float h, float& px, float& pz) {
    int j = (k == 2) ? 0 : (k + 1);
    float yi = v[k * 3 + 1], yj = v[j * 3 + 1];
    if (!((yi - h) * (yj - h) < 0.f)) return false;
    float denom = yj - yi;
    float safe = (fabsf(denom) > 1e-12f) ? denom : 1e-12f;
    float tt = fminf(fmaxf((h - yi) / safe, 0.f), 1.f);
    px = v[k * 3 + 0] + tt * (v[j * 3 + 0] - v[k * 3 + 0]);
    pz = v[k * 3 + 2] + tt * (v[j * 3 + 2] - v[k * 3 + 2]);
    return true;
}

// ---------------------------------------------------------------------------
// K1: coarse supports (+ mass partials for m==0 blocks).  grid = (NCH, 12).
// Ballot-aggregated LDS compaction (1 atomic/wave), 4-way unrolled support.
// ---------------------------------------------------------------------------
__global__ __launch_bounds__(256) void coarse_kernel(
    const float* __restrict__ tris, int F, int NCH,
    const float* __restrict__ bc0, const float* __restrict__ bc1,
    const float* __restrict__ bc2,
    const int* __restrict__ fi0, const int* __restrict__ fi1,
    const int* __restrict__ fi2,
    unsigned int* __restrict__ M_part, float* __restrict__ R2_part,
    float* __restrict__ mass_part) {
    int pair = blockIdx.y, chunk = blockIdx.x;
    int m = pair >> 2, b = pair & 3;
    const float* bc = (m == 0) ? bc0 : ((m == 1) ? bc1 : bc2);
    int fidx = (m == 0) ? fi0[0] : ((m == 1) ? fi1[0] : fi2[0]);
    float h = plane_h(tris, F, b, fidx, bc);
    int tid = threadIdx.x, lane = tid & 63, w = tid >> 6;

    __shared__ float2 sp[SCHUNK];
    __shared__ unsigned int sM[KC];
    __shared__ int cnt;
    __shared__ float redA[4], redB[4];
    if (tid < KC) sM[tid] = 0;
    if (tid == 0) cnt = 0;
    __syncthreads();

    float r2max = 0.f, msum = 0.f;
    int f0 = chunk * CF, fend = min(f0 + CF, F);
    for (int f = f0 + tid; f < fend; f += 256) {
        const float* t = tris + ((size_t)(b * F + f)) * 9;
        float v[9];
#pragma unroll
        for (int i = 0; i < 9; i++) v[i] = t[i];
        if (m == 0) {
            msum += -v[6] * v[4] * v[2] + v[3] * v[7] * v[2]
                    + v[6] * v[1] * v[5] - v[0] * v[7] * v[5]
                    - v[3] * v[1] * v[8] + v[0] * v[4] * v[8];
        }
#pragma unroll
        for (int k = 0; k < 3; k++) {
            float px, pz;
            bool has = crossing(v, k, h, px, pz);
            unsigned long long mask = __ballot(has);
            if (mask) {
                int leader = __ffsll((long long)mask) - 1;
                int base = 0;
                if (lane == leader) base = atomicAdd(&cnt, __popcll(mask));
                base = __shfl(base, leader, 64);
                if (has) {
                    int idx =
                        base + __popcll(mask & ((1ull << lane) - 1ull));
                    sp[idx] = make_float2(px, pz);
                    r2max = fmaxf(r2max, px * px + pz * pz);
                }
            }
        }
    }
    for (int off = 32; off; off >>= 1)
        r2max = fmaxf(r2max, __shfl_down(r2max, off, 64));
    if (lane == 0) redA[w] = r2max;
    if (m == 0) {
        for (int off = 32; off; off >>= 1) msum += __shfl_down(msum, off, 64);
        if (lane == 0) redB[w] = msum;
    }
    __syncthreads();
    if (tid == 0) {
        R2_part[pair * NCH + chunk] =
            fmaxf(fmaxf(redA[0], redA[1]), fmaxf(redA[2], redA[3]));
        if (m == 0)
            mass_part[b * NCH + chunk] = redB[0] + redB[1] + redB[2] + redB[3];
    }

    int n = cnt;
    int d = lane;       // dir = lane (broadcast LDS reads within wave)
    int slice = w;      // 0..3
    float s, c;
    sincosf((float)d * (float)(6.283185307179586 / KC), &s, &c);
    float mv0 = -INFINITY, mv1 = -INFINITY, mv2 = -INFINITY, mv3 = -INFINITY;
    int i = slice;
    for (; i + 12 < n; i += 16) {
        float2 pa = sp[i], pb = sp[i + 4], pc = sp[i + 8], pd = sp[i + 12];
        mv0 = fmaxf(mv0, fmaf(pa.x, c, pa.y * s));
        mv1 = fmaxf(mv1, fmaf(pb.x, c, pb.y * s));
        mv2 = fmaxf(mv2, fmaf(pc.x, c, pc.y * s));
        mv3 = fmaxf(mv3, fmaf(pd.x, c, pd.y * s));
    }
    for (; i < n; i += 4) {
        float2 p = sp[i];
        mv0 = fmaxf(mv0, fmaf(p.x, c, p.y * s));
    }
    float mv = fmaxf(fmaxf(mv0, mv1), fmaxf(mv2, mv3));
    atomicMax(&sM[d], ordf(mv));
    __syncthreads();
    if (tid < KC) M_part[(pair * NCH + chunk) * KC + tid] = sM[tid];
}

// ---------------------------------------------------------------------------
// K2: survivors.  tau = min_d(max_c M) - 0.052*R (support is R-Lipschitz in
// direction; angular gap to nearest coarse dir <= pi/64 -> slack < 0.052R).
// Fully parallel tau reduction; ballot-aggregated survivor writes.
// ---------------------------------------------------------------------------
__global__ __launch_bounds__(256) void surv_kernel(
    const float* __restrict__ tris, int F, int NCH,
    const float* __restrict__ bc0, const float* __restrict__ bc1,
    const float* __restrict__ bc2,
    const int* __restrict__ fi0, const int* __restrict__ fi1,
    const int* __restrict__ fi2,
    const unsigned int* __restrict__ M_part,
    const float* __restrict__ R2_part,
    int* __restrict__ cnt_part, float2* __restrict__ slist) {
    int pair = blockIdx.y, chunk = blockIdx.x;
    int m = pair >> 2, b = pair & 3;
    const float* bc = (m == 0) ? bc0 : ((m == 1) ? bc1 : bc2);
    int fidx = (m == 0) ? fi0[0] : ((m == 1) ? fi1[0] : fi2[0]);
    float h = plane_h(tris, F, b, fidx, bc);
    int tid = threadIdx.x, lane = tid & 63, w = tid >> 6;

    __shared__ unsigned int sMd[KC];
    __shared__ float sR[4];
    __shared__ float tau_s;
    __shared__ int cnt;
    if (tid < KC) sMd[tid] = 0;
    if (tid == 0) cnt = 0;
    __syncthreads();

    {   // per-dir max across chunks, 4-way parallel over chunk slices
        int d = lane, part = w;
        unsigned int mx = 0;
        for (int c2 = part; c2 < NCH; c2 += 4)
            mx = max(mx, M_part[(pair * NCH + c2) * KC + d]);
        atomicMax(&sMd[d], mx);
    }
    {   // block max of R2
        float r2 = 0.f;
        for (int c2 = tid; c2 < NCH; c2 += 256)
            r2 = fmaxf(r2, R2_part[pair * NCH + c2]);
        for (int off = 32; off; off >>= 1)
            r2 = fmaxf(r2, __shfl_down(r2, off, 64));
        if (lane == 0) sR[w] = r2;
    }
    __syncthreads();
    if (tid < 64) {   // min over dirs, combine with R
        float Md = unordf(sMd[tid]);
        for (int off = 32; off; off >>= 1)
            Md = fminf(Md, __shfl_down(Md, off, 64));
        if (tid == 0) {
            float R = sqrtf(fmaxf(fmaxf(sR[0], sR[1]), fmaxf(sR[2], sR[3])));
            tau_s = Md - 0.052f * R;
        }
    }
    __syncthreads();
    float tau = tau_s;
    bool useTau = (tau > 0.f);
    float tau2 = tau * tau;

    float2* seg = slist + (size_t)(pair * NCH + chunk) * SCHUNK;
    int f0 = chunk * CF, fend = min(f0 + CF, F);
    for (int f = f0 + tid; f < fend; f += 256) {
        const float* t = tris + ((size_t)(b * F + f)) * 9;
        float v[9];
#pragma unroll
        for (int i = 0; i < 9; i++) v[i] = t[i];
#pragma unroll
        for (int k = 0; k < 3; k++) {
            float px, pz;
            bool keep = false;
            if (crossing(v, k, h, px, pz)) {
                float r2 = px * px + pz * pz;
                keep = (!useTau || r2 >= tau2);
            }
            unsigned long long mask = __ballot(keep);
            if (mask) {
                int leader = __ffsll((long long)mask) - 1;
                int base = 0;
                if (lane == leader) base = atomicAdd(&cnt, __popcll(mask));
                base = __shfl(base, leader, 64);
                if (keep) {
                    int idx =
                        base + __popcll(mask & ((1ull << lane) - 1ull));
                    seg[idx] = make_float2(px, pz);
                }
            }
        }
    }
    __syncthreads();
    if (tid == 0) cnt_part[pair * NCH + chunk] = cnt;
}

// ---------------------------------------------------------------------------
// K3: final.  Per-pair block: wave-parallel prefix over chunk counts, gather
// survivors -> LDS, 4-way unrolled 720-dir argmax tracking winner coords,
// perimeter reduce.  Block 0 also writes mass and height.
// ---------------------------------------------------------------------------
__global__ __launch_bounds__(256) void final_kernel(
    const float* __restrict__ tris, int F, int NCH,
    const float* __restrict__ htbc, const float* __restrict__ lhbc,
    const int* __restrict__ hti, const int* __restrict__ lhi,
    const int* __restrict__ cnt_part, const float2* __restrict__ slist,
    const float* __restrict__ mass_part, float* __restrict__ out) {
    int pair = blockIdx.x;  // 0..11
    int m = pair >> 2, b = pair & 3;
    int tid = threadIdx.x, lane = tid & 63, w = tid >> 6;

    if (pair == 0) {
        if (tid >= 64 && tid < 68) {
            int bb = tid - 64;
            float s = 0.f;
            for (int c = 0; c < NCH; c++) s += mass_part[bb * NCH + c];
            out[bb] = fabsf(s) / 6.0f * 985.0f;
        }
        if (tid >= 96 && tid < 100) {
            int bb = tid - 96;
            float hy = plane_h(tris, F, bb, hti[0], htbc);
            float ly = plane_h(tris, F, bb, lhi[0], lhbc);
            out[4 + bb] = fabsf(hy - ly);
        }
    }

    __shared__ int soff[NCHMAX];   // exclusive offsets
    __shared__ int scnt_s[NCHMAX];
    __shared__ int ns_s;
    __shared__ float2 sp[LDSCAP];
    __shared__ float ex[NUM_DIRS], ez[NUM_DIRS];
    __shared__ float wsum[4];

    if (tid < 64) {  // wave-parallel inclusive scan of chunk counts
        int v = (tid < NCH) ? cnt_part[pair * NCH + tid] : 0;
        int s = v;
        for (int off = 1; off < 64; off <<= 1) {
            int o = __shfl_up(s, off, 64);
            if (lane >= off) s += o;
        }
        if (tid < NCH) { soff[tid] = s - v; scnt_s[tid] = v; }
        if (tid == 63) ns_s = s;
    }
    __syncthreads();
    int ns = ns_s;

    for (int c = 0; c < NCH; c++) {
        int base = soff[c], nc = scnt_s[c];
        const float2* seg = slist + (size_t)(pair * NCH + c) * SCHUNK;
        for (int i = tid; i < nc; i += 256) {
            int g = base + i;
            if (g < LDSCAP) sp[g] = seg[i];
        }
    }
    __syncthreads();

    const float dth = (float)(6.283185307179586 / NUM_DIRS);
    int d0 = tid, d1 = tid + 256, d2 = tid + 512;
    float c0, s0, c1, s1, c2 = 0.f, s2 = 0.f;
    sincosf((float)d0 * dth, &s0, &c0);
    sincosf((float)d1 * dth, &s1, &c1);
    if (d2 < NUM_DIRS) sincosf((float)d2 * dth, &s2, &c2);

    float bp0 = -INFINITY, bp1 = -INFINITY, bp2 = -INFINITY;
    float bx0 = 0.f, bz0 = 0.f, bx1 = 0.f, bz1 = 0.f, bx2 = 0.f, bz2 = 0.f;
    int nl = min(ns, LDSCAP);
    int i = 0;
    for (; i + 3 < nl; i += 4) {
        float2 pa = sp[i], pb = sp[i + 1], pc = sp[i + 2], pd = sp[i + 3];
        float qa0 = fmaf(pa.x, c0, pa.y * s0), qb0 = fmaf(pb.x, c0, pb.y * s0);
        float qc0 = fmaf(pc.x, c0, pc.y * s0), qd0 = fmaf(pd.x, c0, pd.y * s0);
        if (qa0 > bp0) { bp0 = qa0; bx0 = pa.x; bz0 = pa.y; }
        if (qb0 > bp0) { bp0 = qb0; bx0 = pb.x; bz0 = pb.y; }
        if (qc0 > bp0) { bp0 = qc0; bx0 = pc.x; bz0 = pc.y; }
        if (qd0 > bp0) { bp0 = qd0; bx0 = pd.x; bz0 = pd.y; }
        float qa1 = fmaf(pa.x, c1, pa.y * s1), qb1 = fmaf(pb.x, c1, pb.y * s1);
        float qc1 = fmaf(pc.x, c1, pc.y * s1), qd1 = fmaf(pd.x, c1, pd.y * s1);
        if (qa1 > bp1) { bp1 = qa1; bx1 = pa.x; bz1 = pa.y; }
        if (qb1 > bp1) { bp1 = qb1; bx1 = pb.x; bz1 = pb.y; }
        if (qc1 > bp1) { bp1 = qc1; bx1 = pc.x; bz1 = pc.y; }
        if (qd1 > bp1) { bp1 = qd1; bx1 = pd.x; bz1 = pd.y; }
        float qa2 = fmaf(pa.x, c2, pa.y * s2), qb2 = fmaf(pb.x, c2, pb.y * s2);
        float qc2 = fmaf(pc.x, c2, pc.y * s2), qd2 = fmaf(pd.x, c2, pd.y * s2);
        if (qa2 > bp2) { bp2 = qa2; bx2 = pa.x; bz2 = pa.y; }
        if (qb2 > bp2) { bp2 = qb2; bx2 = pb.x; bz2 = pb.y; }
        if (qc2 > bp2) { bp2 = qc2; bx2 = pc.x; bz2 = pc.y; }
        if (qd2 > bp2) { bp2 = qd2; bx2 = pd.x; bz2 = pd.y; }
    }
    for (; i < nl; i++) {
        float2 p = sp[i];
        float q0 = fmaf(p.x, c0, p.y * s0);
        float q1 = fmaf(p.x, c1, p.y * s1);
        float q2 = fmaf(p.x, c2, p.y * s2);
        if (q0 > bp0) { bp0 = q0; bx0 = p.x; bz0 = p.y; }
        if (q1 > bp1) { bp1 = q1; bx1 = p.x; bz1 = p.y; }
        if (q2 > bp2) { bp2 = q2; bx2 = p.x; bz2 = p.y; }
    }
    if (ns > LDSCAP) {  // degenerate fallback; never taken with this data
        for (int c = 0; c < NCH; c++) {
            int base = soff[c], e = soff[c] + scnt_s[c];
            const float2* seg = slist + (size_t)(pair * NCH + c) * SCHUNK;
            for (int g = max(base, LDSCAP); g < e; g++) {
                float2 p = seg[g - base];
                float q0 = fmaf(p.x, c0, p.y * s0);
                float q1 = fmaf(p.x, c1, p.y * s1);
                float q2 = fmaf(p.x, c2, p.y * s2);
                if (q0 > bp0) { bp0 = q0; bx0 = p.x; bz0 = p.y; }
                if (q1 > bp1) { bp1 = q1; bx1 = p.x; bz1 = p.y; }
                if (q2 > bp2) { bp2 = q2; bx2 = p.x; bz2 = p.y; }
            }
        }
    }
    ex[d0] = bx0; ez[d0] = bz0;
    ex[d1] = bx1; ez[d1] = bz1;
    if (d2 < NUM_DIRS) { ex[d2] = bx2; ez[d2] = bz2; }
    __syncthreads();

    float local = 0.f;
    for (int d = tid; d < NUM_DIRS; d += 256) {
        int dn = (d + 1) % NUM_DIRS;
        float dx = ex[d] - ex[dn];
        float dz = ez[d] - ez[dn];
        local += sqrtf(dx * dx + dz * dz + 1e-20f);
    }
    for (int off = 32; off; off >>= 1) local += __shfl_down(local, off, 64);
    if (lane == 0) wsum[w] = local;
    __syncthreads();
    if (tid == 0)
        out[(2 + m) * 4 + b] = wsum[0] + wsum[1] + wsum[2] + wsum[3];
}

// ---------------------------------------------------------------------------
extern "C" void kernel_launch(void* const* d_in, const int* in_sizes, int n_in,
                              void* d_out, int out_size, void* d_ws,
                              size_t ws_size, hipStream_t stream) {
    const float* tris = (const float*)d_in[0];
    const float* htbc = (const float*)d_in[1];
    const float* lhbc = (const float*)d_in[2];
    const float* cbc  = (const float*)d_in[3];
    const float* bbc  = (const float*)d_in[4];
    const float* hbc  = (const float*)d_in[5];
    const int* hti = (const int*)d_in[6];
    const int* lhi = (const int*)d_in[7];
    const int* cfi = (const int*)d_in[8];
    const int* bfi = (const int*)d_in[9];
    const int* hfi = (const int*)d_in[10];
    float* out = (float*)d_out;

    int F = in_sizes[0] / 36;
    int NCH = (F + CF - 1) / CF;  // 21 for F=20908 (<= NCHMAX)

    // workspace layout: all owned slots, nothing needs pre-zeroing
    char* w = (char*)d_ws;
    size_t off = 0;
    unsigned int* M_part = (unsigned int*)(w + off);
    off += (size_t)NPAIRS * NCH * KC * sizeof(unsigned int);
    float* R2_part = (float*)(w + off);
    off += (size_t)NPAIRS * NCH * sizeof(float);
    int* cnt_part = (int*)(w + off);
    off += (size_t)NPAIRS * NCH * sizeof(int);
    float* mass_part = (float*)(w + off);
    off += (size_t)4 * NCH * sizeof(float);
    off = (off + 255) & ~(size_t)255;
    float2* slist = (float2*)(w + off);

    dim3 g(NCH, NPAIRS);
    coarse_kernel<<<g, 256, 0, stream>>>(tris, F, NCH, cbc, bbc, hbc, cfi,
                                         bfi, hfi, M_part, R2_part, mass_part);
    surv_kernel<<<g, 256, 0, stream>>>(tris, F, NCH, cbc, bbc, hbc, cfi, bfi,
                                       hfi, M_part, R2_part, cnt_part, slist);
    final_kernel<<<NPAIRS, 256, 0, stream>>>(tris, F, NCH, htbc, lhbc, hti,
                                             lhi, cnt_part, slist, mass_part,
                                             out);
}